// Round 10
// baseline (2319.607 us; speedup 1.0000x reference)
//
#include <hip/hip_runtime.h>
#include <math.h>

#define W0F 30.0f
#define NPTS 32768

// f64 sin-path constants: sin(30 z) = sin(2*pi*frac_centered(z * 30/(2*pi)))
#define C_30_OVER_2PI 4.774648292756860070
#define C_2PI         6.283185307179586477

typedef double v4d __attribute__((ext_vector_type(4)));
typedef double v2d __attribute__((ext_vector_type(2)));

// ---- workspace layout (float offsets) ----
#define OFF_M     0ull                  // 4 layers * 8 t * 65536
#define SZ_M      2097152ull
#define OFF_CB    (OFF_M + SZ_M)        // 4*8*256
#define SZ_CB     8192ull
#define OFF_AF    (OFF_CB + SZ_CB)      // 4*8*8192
#define SZ_AF     262144ull
#define OFF_BF    (OFF_AF + SZ_AF)
#define SZ_BF     262144ull
#define OFF_HB    (OFF_BF + SZ_BF)      // 4*8*256
#define SZ_HB     8192ull
#define OFF_NSC   (OFF_HB + SZ_HB)      // 4*256 + 1, pad to 2048
#define SZ_NSC    2048ull
#define OFF_BSWZ  (OFF_NSC + SZ_NSC)    // 64 x 32768 f64, fragment-ordered B
#define SZ_BSWZ   4194304ull            // (in float units; 16B-aligned)
#define OFF_X0    (OFF_BSWZ + SZ_BSWZ)  // ping-pong activation buffers,
#define SZ_X      16777216ull           // 2*32768*256 floats each
#define OFF_X1    (OFF_X0 + SZ_X)
// total = 40,388,608 floats = 161.6 MB

// ---------------------------------------------------------------------------
// S1: per-row L1 scales + all latent-side GEMVs, f64 accumulation, f32 store.
// ---------------------------------------------------------------------------
__global__ __launch_bounds__(256) void setup1(
    const float* __restrict__ latents,
    const float* __restrict__ AwF, const float* __restrict__ AcF,
    const float* __restrict__ AwH, const float* __restrict__ AcH,
    const float* __restrict__ Bw,  const float* __restrict__ Bc,
    const float* __restrict__ hbw, const float* __restrict__ hbc,
    const float* __restrict__ wF,  const float* __restrict__ cF,
    const float* __restrict__ wH,  const float* __restrict__ cH,
    const float* __restrict__ wL,  const float* __restrict__ cL,
    float* __restrict__ AF, float* __restrict__ BFo,
    float* __restrict__ HBo, float* __restrict__ NSC)
{
    __shared__ float lat[1024];
    int tid = threadIdx.x;
    for (int j = tid; j < 1024; j += 256) lat[j] = latents[j];
    __syncthreads();
    int g = blockIdx.x * 256 + tid;
    if (g < 58464) {
        const float* src; float c; float* dst; int stride;
        if (g < 96) {
            src = AwF + g * 128; c = AcF[0]; dst = AF + g; stride = 8192;
        } else if (g < 24672) {
            int q = g - 96; int l = 1 + q / 8192;
            src = AwH + (size_t)q * 128; c = AcH[l - 1];
            dst = AF + (size_t)l * 8 * 8192 + (q % 8192); stride = 8192;
        } else if (g < 57440) {
            int q = g - 24672; int l = q / 8192;
            src = Bw + (size_t)q * 128; c = Bc[l];
            dst = BFo + (size_t)l * 8 * 8192 + (q % 8192); stride = 8192;
        } else {
            int q = g - 57440; int l = q / 256;
            src = hbw + (size_t)q * 128; c = hbc[l];
            dst = HBo + l * 8 * 256 + (q % 256); stride = 256;
        }
        double l1 = 0.0;
        double acc[8] = {0,0,0,0,0,0,0,0};
        for (int kk = 0; kk < 32; ++kk) {
            float4 w4 = ((const float4*)src)[kk];
            l1 += fabs((double)w4.x) + fabs((double)w4.y)
                + fabs((double)w4.z) + fabs((double)w4.w);
            int k = kk * 4;
            #pragma unroll
            for (int t = 0; t < 8; ++t) {
                const float* lp = &lat[t * 128 + k];
                acc[t] = fma((double)w4.x, (double)lp[0], acc[t]);
                acc[t] = fma((double)w4.y, (double)lp[1], acc[t]);
                acc[t] = fma((double)w4.z, (double)lp[2], acc[t]);
                acc[t] = fma((double)w4.w, (double)lp[3], acc[t]);
            }
        }
        double s = fmin(log1p(exp((double)c)) / l1, 1.0);
        #pragma unroll
        for (int t = 0; t < 8; ++t) dst[(size_t)t * stride] = (float)(acc[t] * s);
    } else if (g < 59489) {
        int h = g - 58464;
        if (h < 256) {
            const float* src = wF + h * 3;
            double l1 = fabs((double)src[0]) + fabs((double)src[1]) + fabs((double)src[2]);
            NSC[h] = (float)fmin(log1p(exp((double)cF[0])) / l1, 1.0);
        } else if (h < 1024) {
            int q = h - 256; int l = 1 + q / 256;
            const float* src = wH + (size_t)q * 256;
            double l1 = 0.0;
            for (int kk = 0; kk < 64; ++kk) {
                float4 w4 = ((const float4*)src)[kk];
                l1 += fabs((double)w4.x) + fabs((double)w4.y)
                    + fabs((double)w4.z) + fabs((double)w4.w);
            }
            NSC[256 + q] = (float)fmin(log1p(exp((double)cH[l - 1])) / l1, 1.0);
        } else {
            double l1 = 0.0;
            for (int kk = 0; kk < 64; ++kk) {
                float4 w4 = ((const float4*)wL)[kk];
                l1 += fabs((double)w4.x) + fabs((double)w4.y)
                    + fabs((double)w4.z) + fabs((double)w4.w);
            }
            NSC[1024] = (float)fmin(log1p(exp((double)cL[0])) / l1, 1.0);
        }
    }
}

// ---------------------------------------------------------------------------
// S2: M[l][t][i][o] = W[o,i]*s[o] + sum_r A[i,r]B[r,o]  (f64 acc, f32 store)
// ---------------------------------------------------------------------------
__global__ __launch_bounds__(256) void setup2(
    const float* __restrict__ wF, const float* __restrict__ bF,
    const float* __restrict__ wH, const float* __restrict__ bH,
    const float* __restrict__ AF, const float* __restrict__ BFi,
    const float* __restrict__ HBi, const float* __restrict__ NSC,
    float* __restrict__ Mb, float* __restrict__ CBb)
{
    int b = blockIdx.x; int t = b / 49; int rem = b % 49;
    int o = threadIdx.x;
    int l, i0, ni;
    if (rem == 0) { l = 0; i0 = 0; ni = 3; }
    else { l = 1 + (rem - 1) / 16; i0 = ((rem - 1) % 16) * 16; ni = 16; }
    size_t ltb = (size_t)(l * 8 + t);
    const float* af = AF + ltb * 8192;
    const float* bf = BFi + ltb * 8192;
    double sc = (double)NSC[l * 256 + o];
    float bcol[32];
    #pragma unroll
    for (int r = 0; r < 32; ++r) bcol[r] = bf[r * 256 + o];
    for (int ii = 0; ii < ni; ++ii) {
        int i = i0 + ii;
        float wv = (l == 0) ? wF[o * 3 + i] : wH[(size_t)((l - 1) * 256 + o) * 256 + i];
        double m = (double)wv * sc;
        #pragma unroll
        for (int r = 0; r < 32; ++r)
            m = fma((double)af[i * 32 + r], (double)bcol[r], m);
        Mb[ltb * 65536 + (size_t)i * 256 + o] = (float)m;
    }
    if (rem == 0 || ((rem - 1) % 16) == 0) {
        double bb = (l == 0) ? (double)bF[o] : (double)bH[(l - 1) * 256 + o];
        CBb[ltb * 256 + o] = (float)(bb + (double)HBi[ltb * 256 + o]);
    }
}

// ---------------------------------------------------------------------------
// S3: build fragment-ordered f64 B buffer for the hidden-layer GEMM.
// Bswz[(ltb*2+ch)*32768 + ((s*4 + j)*128 + lane*2 + e)]
//   = (double)M[ltb][(4s+q)*256 + ch*128 + (2j+e)*16 + c16],  lane=16q+c16.
// In the K-loop, instr (s,j) is a dwordx4 of 2 doubles per lane, contiguous
// 1 KB across the wave (perfect coalescing), zero in-loop cvts for B.
// ---------------------------------------------------------------------------
__global__ __launch_bounds__(256) void setup3(
    const float* __restrict__ Mb, double* __restrict__ Bswz)
{
    int gid = blockIdx.x * 256 + threadIdx.x;   // 0 .. 64*32768-1
    int ltc = gid >> 15;                        // (ltb, ch)
    int g   = gid & 32767;
    int e    = g & 1;
    int lane = (g >> 1) & 63;
    int j    = (g >> 7) & 3;
    int s    = g >> 9;
    int q = lane >> 4, c16 = lane & 15;
    int ltb = ltc >> 1, ch = ltc & 1;
    float v = Mb[(size_t)ltb * 65536 + (size_t)(4 * s + q) * 256
                 + ch * 128 + (2 * j + e) * 16 + c16];
    Bswz[gid] = (double)v;
}

// precise activation: sin(30*z) via f64 range reduction + f32 sin on [-pi,pi]
__device__ __forceinline__ float sin30(double z) {
    double u = z * C_30_OVER_2PI;
    double r = u - rint(u);
    return sinf((float)(r * C_2PI));
}

// ---------------------------------------------------------------------------
// L0: x = sin(30*(coords @ M0 + cb)), f64 per element (K=3).
// ---------------------------------------------------------------------------
__global__ __launch_bounds__(256) void layer0_k(
    const float* __restrict__ coords, const float* __restrict__ Mb,
    const float* __restrict__ CBb, float* __restrict__ X, int tbase)
{
    __shared__ float Ms[3][256];
    __shared__ float cbs[256];
    int tid = threadIdx.x;
    int tl = blockIdx.x >> 10; int rb = blockIdx.x & 1023;
    int t = tbase + tl;
    const float* Mt = Mb + (size_t)t * 65536;
    Ms[0][tid] = Mt[tid]; Ms[1][tid] = Mt[256 + tid]; Ms[2][tid] = Mt[512 + tid];
    cbs[tid] = CBb[t * 256 + tid];
    __syncthreads();
    int r = rb * 32 + (tid >> 3); int lane8 = tid & 7;
    const float* cp = coords + ((size_t)t * NPTS + r) * 3;
    double c0 = (double)cp[0], c1 = (double)cp[1], c2 = (double)cp[2];
    float* xo = X + ((size_t)tl * NPTS + r) * 256;
#define L0E(col) sin30(fma(c2, (double)Ms[2][col], fma(c1, (double)Ms[1][col], \
                  fma(c0, (double)Ms[0][col], (double)cbs[col]))))
    #pragma unroll
    for (int j = 0; j < 8; ++j) {
        int col = 4 * lane8 + 32 * j;
        float4 v;
        v.x = L0E(col + 0);
        v.y = L0E(col + 1);
        v.z = L0E(col + 2);
        v.w = L0E(col + 3);
        *(float4*)(xo + col) = v;
    }
#undef L0E
}

// ---------------------------------------------------------------------------
// Hidden layer via f64 MFMA, BARRIER-FREE K-loop, Xsrc -> Xdst (ping-pong),
// one-deep register pipeline + FRAGMENT-ORDERED f64 B (Bswz): per k-step the
// B path is 4 fully-coalesced dwordx4 loads, 0 cvts (round-9 lesson: 8 scalar
// B loads + 9 cvts per step = issue tax that pinned MfmaUtil at 65%).
// A stays scalar f32 from X (1 load + 1 cvt / step, L1-resident lines).
// Grid 2048 = tl(2) x row-tile(512 of 64 rows) x col-half(2 of 128 cols).
// C/D layout discovered at runtime by two probe MFMAs (round-5 lesson).
// ---------------------------------------------------------------------------
__global__ __launch_bounds__(256, 4) void gemm_sin(
    const float* __restrict__ Xsrc, float* __restrict__ Xdst,
    const double* __restrict__ Bswz, const float* __restrict__ CBb,
    int l, int tbase)
{
    int tid = threadIdx.x;
    int b = blockIdx.x;
    int tl = b >> 10;
    int rb = (b >> 1) & 511;
    int ch = b & 1;
    size_t ltb = (size_t)(l * 8 + tbase + tl);
    const float* cbp = CBb + ltb * 256 + ch * 128;
    const float* Xs = Xsrc + ((size_t)tl * NPTS + rb * 64) * 256;
    float*       Xd = Xdst + ((size_t)tl * NPTS + rb * 64) * 256 + ch * 128;
    int wave = tid >> 6, lane = tid & 63;
    int q = lane >> 4, c16 = lane & 15;
    // --- D-layout probe (layout-agnostic epilogue indices) ---
    v4d zz = {0., 0., 0., 0.};
    v4d p1 = __builtin_amdgcn_mfma_f64_16x16x4f64((double)(1 << c16), 1.0, zz, 0, 0, 0);
    v4d p2 = __builtin_amdgcn_mfma_f64_16x16x4f64(1.0, (double)(1 << c16), zz, 0, 0, 0);
    int r0 = 61 - __builtin_clzll((unsigned long long)p1[0]);
    int r1 = 61 - __builtin_clzll((unsigned long long)p1[1]);
    int r2 = 61 - __builtin_clzll((unsigned long long)p1[2]);
    int r3 = 61 - __builtin_clzll((unsigned long long)p1[3]);
    int c0 = 61 - __builtin_clzll((unsigned long long)p2[0]);
    int c1 = 61 - __builtin_clzll((unsigned long long)p2[1]);
    int c2 = 61 - __builtin_clzll((unsigned long long)p2[2]);
    int c3 = 61 - __builtin_clzll((unsigned long long)p2[3]);
    // fragment pointers: A[m=c16][k=q+4s]; Bswz lane-block (2 doubles/slot)
    const float* ap = Xs + (size_t)(wave * 16 + c16) * 256 + q;
    const double* bzl = Bswz + ((size_t)ltb * 2 + ch) * 32768 + lane * 2;
    v4d acc0 = {0.,0.,0.,0.}, acc1 = {0.,0.,0.,0.}, acc2 = {0.,0.,0.,0.},
        acc3 = {0.,0.,0.,0.}, acc4 = {0.,0.,0.,0.}, acc5 = {0.,0.,0.,0.},
        acc6 = {0.,0.,0.,0.}, acc7 = {0.,0.,0.,0.};
    // prologue: fragments for s=0
    float aC  = ap[0];
    v2d bC0 = *(const v2d*)(bzl + 0 * 128);
    v2d bC1 = *(const v2d*)(bzl + 1 * 128);
    v2d bC2 = *(const v2d*)(bzl + 2 * 128);
    v2d bC3 = *(const v2d*)(bzl + 3 * 128);
    #pragma unroll 4
    for (int s = 0; s < 64; ++s) {
        int sn = (s < 63) ? s + 1 : 63;          // last prefetch is redundant
        float aN = ap[4 * sn];
        const double* bn = bzl + (size_t)sn * 512;
        v2d bN0 = *(const v2d*)(bn + 0 * 128);
        v2d bN1 = *(const v2d*)(bn + 1 * 128);
        v2d bN2 = *(const v2d*)(bn + 2 * 128);
        v2d bN3 = *(const v2d*)(bn + 3 * 128);
        double av = (double)aC;
#define TILE(n, bv) { acc##n = __builtin_amdgcn_mfma_f64_16x16x4f64(          \
                               av, (bv), acc##n, 0, 0, 0); }
        TILE(0, bC0.x) TILE(1, bC0.y) TILE(2, bC1.x) TILE(3, bC1.y)
        TILE(4, bC2.x) TILE(5, bC2.y) TILE(6, bC3.x) TILE(7, bC3.y)
#undef TILE
        aC = aN;
        bC0 = bN0; bC1 = bN1; bC2 = bN2; bC3 = bN3;
    }
    // epilogue: reg r of this lane holds D[row_r][col_r] of the wave's tile n
    float* Xw = Xd + (size_t)(wave * 16) * 256;
#define EPT(n) {                                                               \
        int cb0 = (n) * 16;                                                    \
        Xw[r0 * 256 + cb0 + c0] = sin30(acc##n[0] + (double)cbp[cb0 + c0]);    \
        Xw[r1 * 256 + cb0 + c1] = sin30(acc##n[1] + (double)cbp[cb0 + c1]);    \
        Xw[r2 * 256 + cb0 + c2] = sin30(acc##n[2] + (double)cbp[cb0 + c2]);    \
        Xw[r3 * 256 + cb0 + c3] = sin30(acc##n[3] + (double)cbp[cb0 + c3]); }
    EPT(0) EPT(1) EPT(2) EPT(3)
    EPT(4) EPT(5) EPT(6) EPT(7)
#undef EPT
}

// ---------------------------------------------------------------------------
// Final: out[row] = (x_row . w_last)*scale + b_last, f64 dot. One wave per row.
// ---------------------------------------------------------------------------
__global__ __launch_bounds__(256) void final_k(
    const float* __restrict__ X, const float* __restrict__ wl,
    const float* __restrict__ bl, const float* __restrict__ NSC,
    float* __restrict__ out, int tbase)
{
    int tid = threadIdx.x; int w = tid >> 6; int lane = tid & 63;
    size_t row = (size_t)blockIdx.x * 4 + w;      // local row within 2 t's
    double ls = (double)NSC[1024];
    float4 wv = ((const float4*)wl)[lane];
    float4 xv = *(const float4*)(X + row * 256 + lane * 4);
    double d = 0.0;
    d = fma((double)wv.x, (double)xv.x, d);
    d = fma((double)wv.y, (double)xv.y, d);
    d = fma((double)wv.z, (double)xv.z, d);
    d = fma((double)wv.w, (double)xv.w, d);
    d *= ls;
    #pragma unroll
    for (int off = 32; off > 0; off >>= 1) d += __shfl_down(d, off, 64);
    if (lane == 0) out[(size_t)tbase * NPTS + row] = (float)(d + (double)bl[0]);
}

extern "C" void kernel_launch(void* const* d_in, const int* in_sizes, int n_in,
                              void* d_out, int out_size, void* d_ws, size_t ws_size,
                              hipStream_t stream)
{
    const float* coords     = (const float*)d_in[0];
    const float* latents    = (const float*)d_in[1];
    const float* nf_w_first = (const float*)d_in[2];
    const float* nf_b_first = (const float*)d_in[3];
    const float* nf_c_first = (const float*)d_in[4];
    const float* nf_w_hid   = (const float*)d_in[5];
    const float* nf_b_hid   = (const float*)d_in[6];
    const float* nf_c_hid   = (const float*)d_in[7];
    const float* nf_w_last  = (const float*)d_in[8];
    const float* nf_b_last  = (const float*)d_in[9];
    const float* nf_c_last  = (const float*)d_in[10];
    const float* Aw_first   = (const float*)d_in[11];
    const float* Ac_first   = (const float*)d_in[12];
    const float* Aw_hid     = (const float*)d_in[13];
    const float* Ac_hid     = (const float*)d_in[14];
    const float* Bw         = (const float*)d_in[15];
    const float* Bc         = (const float*)d_in[16];
    const float* hbw        = (const float*)d_in[17];
    const float* hbc        = (const float*)d_in[18];

    float* ws  = (float*)d_ws;
    float* Mb  = ws + OFF_M;
    float* CBb = ws + OFF_CB;
    float* AF  = ws + OFF_AF;
    float* BFb = ws + OFF_BF;
    float* HBb = ws + OFF_HB;
    float* NSC = ws + OFF_NSC;
    double* Bz = (double*)(ws + OFF_BSWZ);
    float* X0  = ws + OFF_X0;
    float* X1  = ws + OFF_X1;
    float* out = (float*)d_out;

    setup1<<<233, 256, 0, stream>>>(latents, Aw_first, Ac_first, Aw_hid, Ac_hid,
                                    Bw, Bc, hbw, hbc,
                                    nf_w_first, nf_c_first, nf_w_hid, nf_c_hid,
                                    nf_w_last, nf_c_last,
                                    AF, BFb, HBb, NSC);
    setup2<<<392, 256, 0, stream>>>(nf_w_first, nf_b_first, nf_w_hid, nf_b_hid,
                                    AF, BFb, HBb, NSC, Mb, CBb);
    setup3<<<8192, 256, 0, stream>>>(Mb, Bz);
    for (int tbase = 0; tbase < 8; tbase += 2) {
        layer0_k<<<2048, 256, 0, stream>>>(coords, Mb, CBb, X0, tbase);
        gemm_sin<<<2048, 256, 0, stream>>>(X0, X1, Bz, CBb, 1, tbase);
        gemm_sin<<<2048, 256, 0, stream>>>(X1, X0, Bz, CBb, 2, tbase);
        gemm_sin<<<2048, 256, 0, stream>>>(X0, X1, Bz, CBb, 3, tbase);
        final_k<<<16384, 256, 0, stream>>>(X1, nf_w_last, nf_b_last, NSC, out, tbase);
    }
}

// Round 11
// 2104.270 us; speedup vs baseline: 1.1023x; 1.1023x over previous
//
#include <hip/hip_runtime.h>
#include <math.h>

#define W0F 30.0f
#define NPTS 32768

// f64 sin-path constants: sin(30 z) = sin(2*pi*frac_centered(z * 30/(2*pi)))
#define C_30_OVER_2PI 4.774648292756860070
#define C_2PI         6.283185307179586477

typedef double v4d __attribute__((ext_vector_type(4)));

// ---- workspace layout (float offsets) ----
#define OFF_M     0ull                  // 4 layers * 8 t * 65536
#define SZ_M      2097152ull
#define OFF_CB    (OFF_M + SZ_M)        // 4*8*256
#define SZ_CB     8192ull
#define OFF_AF    (OFF_CB + SZ_CB)      // 4*8*8192
#define SZ_AF     262144ull
#define OFF_BF    (OFF_AF + SZ_AF)
#define SZ_BF     262144ull
#define OFF_HB    (OFF_BF + SZ_BF)      // 4*8*256
#define SZ_HB     8192ull
#define OFF_NSC   (OFF_HB + SZ_HB)      // 4*256 + 1, pad to 2048
#define SZ_NSC    2048ull
#define OFF_BSWZ  (OFF_NSC + SZ_NSC)    // 64 slices x 32768 f32, fragment order
#define SZ_BSWZ   2097152ull
#define OFF_X0    (OFF_BSWZ + SZ_BSWZ)  // ping-pong activation buffers,
#define SZ_X      16777216ull           // 2*32768*256 floats each
#define OFF_X1    (OFF_X0 + SZ_X)
// total = 38.3 M floats = 153 MB

// ---------------------------------------------------------------------------
// S1: per-row L1 scales + all latent-side GEMVs, f64 accumulation, f32 store.
// ---------------------------------------------------------------------------
__global__ __launch_bounds__(256) void setup1(
    const float* __restrict__ latents,
    const float* __restrict__ AwF, const float* __restrict__ AcF,
    const float* __restrict__ AwH, const float* __restrict__ AcH,
    const float* __restrict__ Bw,  const float* __restrict__ Bc,
    const float* __restrict__ hbw, const float* __restrict__ hbc,
    const float* __restrict__ wF,  const float* __restrict__ cF,
    const float* __restrict__ wH,  const float* __restrict__ cH,
    const float* __restrict__ wL,  const float* __restrict__ cL,
    float* __restrict__ AF, float* __restrict__ BFo,
    float* __restrict__ HBo, float* __restrict__ NSC)
{
    __shared__ float lat[1024];
    int tid = threadIdx.x;
    for (int j = tid; j < 1024; j += 256) lat[j] = latents[j];
    __syncthreads();
    int g = blockIdx.x * 256 + tid;
    if (g < 58464) {
        const float* src; float c; float* dst; int stride;
        if (g < 96) {
            src = AwF + g * 128; c = AcF[0]; dst = AF + g; stride = 8192;
        } else if (g < 24672) {
            int q = g - 96; int l = 1 + q / 8192;
            src = AwH + (size_t)q * 128; c = AcH[l - 1];
            dst = AF + (size_t)l * 8 * 8192 + (q % 8192); stride = 8192;
        } else if (g < 57440) {
            int q = g - 24672; int l = q / 8192;
            src = Bw + (size_t)q * 128; c = Bc[l];
            dst = BFo + (size_t)l * 8 * 8192 + (q % 8192); stride = 8192;
        } else {
            int q = g - 57440; int l = q / 256;
            src = hbw + (size_t)q * 128; c = hbc[l];
            dst = HBo + l * 8 * 256 + (q % 256); stride = 256;
        }
        double l1 = 0.0;
        double acc[8] = {0,0,0,0,0,0,0,0};
        for (int kk = 0; kk < 32; ++kk) {
            float4 w4 = ((const float4*)src)[kk];
            l1 += fabs((double)w4.x) + fabs((double)w4.y)
                + fabs((double)w4.z) + fabs((double)w4.w);
            int k = kk * 4;
            #pragma unroll
            for (int t = 0; t < 8; ++t) {
                const float* lp = &lat[t * 128 + k];
                acc[t] = fma((double)w4.x, (double)lp[0], acc[t]);
                acc[t] = fma((double)w4.y, (double)lp[1], acc[t]);
                acc[t] = fma((double)w4.z, (double)lp[2], acc[t]);
                acc[t] = fma((double)w4.w, (double)lp[3], acc[t]);
            }
        }
        double s = fmin(log1p(exp((double)c)) / l1, 1.0);
        #pragma unroll
        for (int t = 0; t < 8; ++t) dst[(size_t)t * stride] = (float)(acc[t] * s);
    } else if (g < 59489) {
        int h = g - 58464;
        if (h < 256) {
            const float* src = wF + h * 3;
            double l1 = fabs((double)src[0]) + fabs((double)src[1]) + fabs((double)src[2]);
            NSC[h] = (float)fmin(log1p(exp((double)cF[0])) / l1, 1.0);
        } else if (h < 1024) {
            int q = h - 256; int l = 1 + q / 256;
            const float* src = wH + (size_t)q * 256;
            double l1 = 0.0;
            for (int kk = 0; kk < 64; ++kk) {
                float4 w4 = ((const float4*)src)[kk];
                l1 += fabs((double)w4.x) + fabs((double)w4.y)
                    + fabs((double)w4.z) + fabs((double)w4.w);
            }
            NSC[256 + q] = (float)fmin(log1p(exp((double)cH[l - 1])) / l1, 1.0);
        } else {
            double l1 = 0.0;
            for (int kk = 0; kk < 64; ++kk) {
                float4 w4 = ((const float4*)wL)[kk];
                l1 += fabs((double)w4.x) + fabs((double)w4.y)
                    + fabs((double)w4.z) + fabs((double)w4.w);
            }
            NSC[1024] = (float)fmin(log1p(exp((double)cL[0])) / l1, 1.0);
        }
    }
}

// ---------------------------------------------------------------------------
// S2: M[l][t][i][o] = W[o,i]*s[o] + sum_r A[i,r]B[r,o]  (f64 acc, f32 store)
// ---------------------------------------------------------------------------
__global__ __launch_bounds__(256) void setup2(
    const float* __restrict__ wF, const float* __restrict__ bF,
    const float* __restrict__ wH, const float* __restrict__ bH,
    const float* __restrict__ AF, const float* __restrict__ BFi,
    const float* __restrict__ HBi, const float* __restrict__ NSC,
    float* __restrict__ Mb, float* __restrict__ CBb)
{
    int b = blockIdx.x; int t = b / 49; int rem = b % 49;
    int o = threadIdx.x;
    int l, i0, ni;
    if (rem == 0) { l = 0; i0 = 0; ni = 3; }
    else { l = 1 + (rem - 1) / 16; i0 = ((rem - 1) % 16) * 16; ni = 16; }
    size_t ltb = (size_t)(l * 8 + t);
    const float* af = AF + ltb * 8192;
    const float* bf = BFi + ltb * 8192;
    double sc = (double)NSC[l * 256 + o];
    float bcol[32];
    #pragma unroll
    for (int r = 0; r < 32; ++r) bcol[r] = bf[r * 256 + o];
    for (int ii = 0; ii < ni; ++ii) {
        int i = i0 + ii;
        float wv = (l == 0) ? wF[o * 3 + i] : wH[(size_t)((l - 1) * 256 + o) * 256 + i];
        double m = (double)wv * sc;
        #pragma unroll
        for (int r = 0; r < 32; ++r)
            m = fma((double)af[i * 32 + r], (double)bcol[r], m);
        Mb[ltb * 65536 + (size_t)i * 256 + o] = (float)m;
    }
    if (rem == 0 || ((rem - 1) % 16) == 0) {
        double bb = (l == 0) ? (double)bF[o] : (double)bH[(l - 1) * 256 + o];
        CBb[ltb * 256 + o] = (float)(bb + (double)HBi[ltb * 256 + o]);
    }
}

// ---------------------------------------------------------------------------
// S3: fragment-ordered **f32** B buffer (round-10 lesson: f64 swizzle doubled
// VMEM bytes and regressed; f32 keeps bytes at round-9 level with 4x fewer
// B-load instructions — 2 coalesced dwordx4 per k-step).
// Layout: slice (ltb,ch); element ((s*2 + h)*64 + lane)*4 + e holds
//   B[k=4s+q][n=(4h+e)*16 + c16] with lane = 16q + c16.
// ---------------------------------------------------------------------------
__global__ __launch_bounds__(256) void setup3(
    const float* __restrict__ Mb, float* __restrict__ Bswz)
{
    int gid = blockIdx.x * 256 + threadIdx.x;   // 0 .. 64*32768-1
    int e    = gid & 3;
    int lane = (gid >> 2) & 63;
    int h    = (gid >> 8) & 1;
    int s    = (gid >> 9) & 63;
    int ltc  = gid >> 15;                       // (ltb, ch)
    int q = lane >> 4, c16 = lane & 15;
    int ltb = ltc >> 1, ch = ltc & 1;
    int n = h * 4 + e;
    Bswz[gid] = Mb[(size_t)ltb * 65536 + (size_t)(4 * s + q) * 256
                   + ch * 128 + n * 16 + c16];
}

// precise activation: sin(30*z) via f64 range reduction + f32 sin on [-pi,pi]
__device__ __forceinline__ float sin30(double z) {
    double u = z * C_30_OVER_2PI;
    double r = u - rint(u);
    return sinf((float)(r * C_2PI));
}

// ---------------------------------------------------------------------------
// L0: x = sin(30*(coords @ M0 + cb)), f64 per element (K=3).
// ---------------------------------------------------------------------------
__global__ __launch_bounds__(256) void layer0_k(
    const float* __restrict__ coords, const float* __restrict__ Mb,
    const float* __restrict__ CBb, float* __restrict__ X, int tbase)
{
    __shared__ float Ms[3][256];
    __shared__ float cbs[256];
    int tid = threadIdx.x;
    int tl = blockIdx.x >> 10; int rb = blockIdx.x & 1023;
    int t = tbase + tl;
    const float* Mt = Mb + (size_t)t * 65536;
    Ms[0][tid] = Mt[tid]; Ms[1][tid] = Mt[256 + tid]; Ms[2][tid] = Mt[512 + tid];
    cbs[tid] = CBb[t * 256 + tid];
    __syncthreads();
    int r = rb * 32 + (tid >> 3); int lane8 = tid & 7;
    const float* cp = coords + ((size_t)t * NPTS + r) * 3;
    double c0 = (double)cp[0], c1 = (double)cp[1], c2 = (double)cp[2];
    float* xo = X + ((size_t)tl * NPTS + r) * 256;
#define L0E(col) sin30(fma(c2, (double)Ms[2][col], fma(c1, (double)Ms[1][col], \
                  fma(c0, (double)Ms[0][col], (double)cbs[col]))))
    #pragma unroll
    for (int j = 0; j < 8; ++j) {
        int col = 4 * lane8 + 32 * j;
        float4 v;
        v.x = L0E(col + 0);
        v.y = L0E(col + 1);
        v.z = L0E(col + 2);
        v.w = L0E(col + 3);
        *(float4*)(xo + col) = v;
    }
#undef L0E
}

// ---------------------------------------------------------------------------
// Hidden layer via f64 MFMA, BARRIER-FREE K-loop, Xsrc -> Xdst (ping-pong),
// TWO-DEEP register pipeline (C<-N<-NN rotation): MFMAs at step s consume
// registers loaded at step s-2 — guaranteed landed regardless of L2 latency
// (round-9/10 lesson: 1-deep left a partial latency stall, MfmaUtil 60-65%).
// B: fragment-ordered f32 Bswz -> 2 coalesced dwordx4 per step (bytes =
// round 9, instrs = round 10's best). cvts f32->f64 ride the idle VALU.
// Grid 2048 = tl(2) x row-tile(512 of 64 rows) x col-half(2 of 128 cols).
// C/D layout discovered at runtime by two probe MFMAs (round-5 lesson).
// ---------------------------------------------------------------------------
__global__ __launch_bounds__(256, 4) void gemm_sin(
    const float* __restrict__ Xsrc, float* __restrict__ Xdst,
    const float* __restrict__ Bswz, const float* __restrict__ CBb,
    int l, int tbase)
{
    int tid = threadIdx.x;
    int b = blockIdx.x;
    int tl = b >> 10;
    int rb = (b >> 1) & 511;
    int ch = b & 1;
    size_t ltb = (size_t)(l * 8 + tbase + tl);
    const float* cbp = CBb + ltb * 256 + ch * 128;
    const float* Xs = Xsrc + ((size_t)tl * NPTS + rb * 64) * 256;
    float*       Xd = Xdst + ((size_t)tl * NPTS + rb * 64) * 256 + ch * 128;
    int wave = tid >> 6, lane = tid & 63;
    int q = lane >> 4, c16 = lane & 15;
    // --- D-layout probe (layout-agnostic epilogue indices) ---
    v4d zz = {0., 0., 0., 0.};
    v4d p1 = __builtin_amdgcn_mfma_f64_16x16x4f64((double)(1 << c16), 1.0, zz, 0, 0, 0);
    v4d p2 = __builtin_amdgcn_mfma_f64_16x16x4f64(1.0, (double)(1 << c16), zz, 0, 0, 0);
    int r0 = 61 - __builtin_clzll((unsigned long long)p1[0]);
    int r1 = 61 - __builtin_clzll((unsigned long long)p1[1]);
    int r2 = 61 - __builtin_clzll((unsigned long long)p1[2]);
    int r3 = 61 - __builtin_clzll((unsigned long long)p1[3]);
    int c0 = 61 - __builtin_clzll((unsigned long long)p2[0]);
    int c1 = 61 - __builtin_clzll((unsigned long long)p2[1]);
    int c2 = 61 - __builtin_clzll((unsigned long long)p2[2]);
    int c3 = 61 - __builtin_clzll((unsigned long long)p2[3]);
    // fragment pointers: A[m=c16][k=q+4s]; Bswz lane slot (4 f32 per instr)
    const float* ap  = Xs + (size_t)(wave * 16 + c16) * 256 + q;
    const float* bzl = Bswz + ((size_t)ltb * 2 + ch) * 32768 + lane * 4;
    v4d acc0 = {0.,0.,0.,0.}, acc1 = {0.,0.,0.,0.}, acc2 = {0.,0.,0.,0.},
        acc3 = {0.,0.,0.,0.}, acc4 = {0.,0.,0.,0.}, acc5 = {0.,0.,0.,0.},
        acc6 = {0.,0.,0.,0.}, acc7 = {0.,0.,0.,0.};
    // prologue: fragments for s=0 (C) and s=1 (N)
    float  aC  = ap[0];
    float4 bC0 = *(const float4*)(bzl + 0 * 256);
    float4 bC1 = *(const float4*)(bzl + 1 * 256);
    float  aN  = ap[4];
    float4 bN0 = *(const float4*)(bzl + 2 * 256);
    float4 bN1 = *(const float4*)(bzl + 3 * 256);
    #pragma unroll 2
    for (int s = 0; s < 64; ++s) {
        int s2 = (s < 62) ? s + 2 : 63;          // tail prefetch is redundant
        float  aNN  = ap[4 * s2];
        float4 bNN0 = *(const float4*)(bzl + (s2 * 2 + 0) * 256);
        float4 bNN1 = *(const float4*)(bzl + (s2 * 2 + 1) * 256);
        double av = (double)aC;
#define TILE(n, bf) { acc##n = __builtin_amdgcn_mfma_f64_16x16x4f64(          \
                               av, (double)(bf), acc##n, 0, 0, 0); }
        TILE(0, bC0.x) TILE(1, bC0.y) TILE(2, bC0.z) TILE(3, bC0.w)
        TILE(4, bC1.x) TILE(5, bC1.y) TILE(6, bC1.z) TILE(7, bC1.w)
#undef TILE
        aC = aN;  aN = aNN;
        bC0 = bN0; bC1 = bN1; bN0 = bNN0; bN1 = bNN1;
    }
    // epilogue: reg r of this lane holds D[row_r][col_r] of the wave's tile n
    float* Xw = Xd + (size_t)(wave * 16) * 256;
#define EPT(n) {                                                               \
        int cb0 = (n) * 16;                                                    \
        Xw[r0 * 256 + cb0 + c0] = sin30(acc##n[0] + (double)cbp[cb0 + c0]);    \
        Xw[r1 * 256 + cb0 + c1] = sin30(acc##n[1] + (double)cbp[cb0 + c1]);    \
        Xw[r2 * 256 + cb0 + c2] = sin30(acc##n[2] + (double)cbp[cb0 + c2]);    \
        Xw[r3 * 256 + cb0 + c3] = sin30(acc##n[3] + (double)cbp[cb0 + c3]); }
    EPT(0) EPT(1) EPT(2) EPT(3)
    EPT(4) EPT(5) EPT(6) EPT(7)
#undef EPT
}

// ---------------------------------------------------------------------------
// Final: out[row] = (x_row . w_last)*scale + b_last, f64 dot. One wave per row.
// ---------------------------------------------------------------------------
__global__ __launch_bounds__(256) void final_k(
    const float* __restrict__ X, const float* __restrict__ wl,
    const float* __restrict__ bl, const float* __restrict__ NSC,
    float* __restrict__ out, int tbase)
{
    int tid = threadIdx.x; int w = tid >> 6; int lane = tid & 63;
    size_t row = (size_t)blockIdx.x * 4 + w;      // local row within 2 t's
    double ls = (double)NSC[1024];
    float4 wv = ((const float4*)wl)[lane];
    float4 xv = *(const float4*)(X + row * 256 + lane * 4);
    double d = 0.0;
    d = fma((double)wv.x, (double)xv.x, d);
    d = fma((double)wv.y, (double)xv.y, d);
    d = fma((double)wv.z, (double)xv.z, d);
    d = fma((double)wv.w, (double)xv.w, d);
    d *= ls;
    #pragma unroll
    for (int off = 32; off > 0; off >>= 1) d += __shfl_down(d, off, 64);
    if (lane == 0) out[(size_t)tbase * NPTS + row] = (float)(d + (double)bl[0]);
}

extern "C" void kernel_launch(void* const* d_in, const int* in_sizes, int n_in,
                              void* d_out, int out_size, void* d_ws, size_t ws_size,
                              hipStream_t stream)
{
    const float* coords     = (const float*)d_in[0];
    const float* latents    = (const float*)d_in[1];
    const float* nf_w_first = (const float*)d_in[2];
    const float* nf_b_first = (const float*)d_in[3];
    const float* nf_c_first = (const float*)d_in[4];
    const float* nf_w_hid   = (const float*)d_in[5];
    const float* nf_b_hid   = (const float*)d_in[6];
    const float* nf_c_hid   = (const float*)d_in[7];
    const float* nf_w_last  = (const float*)d_in[8];
    const float* nf_b_last  = (const float*)d_in[9];
    const float* nf_c_last  = (const float*)d_in[10];
    const float* Aw_first   = (const float*)d_in[11];
    const float* Ac_first   = (const float*)d_in[12];
    const float* Aw_hid     = (const float*)d_in[13];
    const float* Ac_hid     = (const float*)d_in[14];
    const float* Bw         = (const float*)d_in[15];
    const float* Bc         = (const float*)d_in[16];
    const float* hbw        = (const float*)d_in[17];
    const float* hbc        = (const float*)d_in[18];

    float* ws  = (float*)d_ws;
    float* Mb  = ws + OFF_M;
    float* CBb = ws + OFF_CB;
    float* AF  = ws + OFF_AF;
    float* BFb = ws + OFF_BF;
    float* HBb = ws + OFF_HB;
    float* NSC = ws + OFF_NSC;
    float* Bz  = ws + OFF_BSWZ;
    float* X0  = ws + OFF_X0;
    float* X1  = ws + OFF_X1;
    float* out = (float*)d_out;

    setup1<<<233, 256, 0, stream>>>(latents, Aw_first, Ac_first, Aw_hid, Ac_hid,
                                    Bw, Bc, hbw, hbc,
                                    nf_w_first, nf_c_first, nf_w_hid, nf_c_hid,
                                    nf_w_last, nf_c_last,
                                    AF, BFb, HBb, NSC);
    setup2<<<392, 256, 0, stream>>>(nf_w_first, nf_b_first, nf_w_hid, nf_b_hid,
                                    AF, BFb, HBb, NSC, Mb, CBb);
    setup3<<<8192, 256, 0, stream>>>(Mb, Bz);
    for (int tbase = 0; tbase < 8; tbase += 2) {
        layer0_k<<<2048, 256, 0, stream>>>(coords, Mb, CBb, X0, tbase);
        gemm_sin<<<2048, 256, 0, stream>>>(X0, X1, Bz, CBb, 1, tbase);
        gemm_sin<<<2048, 256, 0, stream>>>(X1, X0, Bz, CBb, 2, tbase);
        gemm_sin<<<2048, 256, 0, stream>>>(X0, X1, Bz, CBb, 3, tbase);
        final_k<<<16384, 256, 0, stream>>>(X1, nf_w_last, nf_b_last, NSC, out, tbase);
    }
}